// Round 7
// baseline (1136.654 us; speedup 1.0000x reference)
//
#include <hip/hip_runtime.h>

typedef unsigned short ushort_t;
typedef unsigned int uint32;
typedef __bf16 bf16x8 __attribute__((ext_vector_type(8)));
typedef float f32x4 __attribute__((ext_vector_type(4)));
typedef uint32 u32x4 __attribute__((ext_vector_type(4)));
typedef uint32 u32x2 __attribute__((ext_vector_type(2)));

typedef __attribute__((address_space(3))) uint32 as3_u32;
typedef const __attribute__((address_space(1))) uint32 as1_u32c;

#define NWG 1280

// async global->LDS, 16B per lane; LDS dest = wave-uniform base + lane*16
__device__ __forceinline__ void gl_lds16(const ushort_t* g, ushort_t* l) {
    __builtin_amdgcn_global_load_lds((as1_u32c*)g, (as3_u32*)l, 16, 0, 0);
}

__device__ __forceinline__ float bf2f(ushort_t u) {
    uint32 x = ((uint32)u) << 16;
    return __builtin_bit_cast(float, x);
}
__device__ __forceinline__ ushort_t f2bf(float f) {
    uint32 x = __builtin_bit_cast(uint32, f);
    x += 0x7fffu + ((x >> 16) & 1u);   // RNE
    return (ushort_t)(x >> 16);
}
__device__ __forceinline__ void ld4bf(const ushort_t* p, float* f) {
    const u32x2 w = *(const u32x2*)p;
    f[0] = bf2f((ushort_t)(w[0] & 0xffffu)); f[1] = bf2f((ushort_t)(w[0] >> 16));
    f[2] = bf2f((ushort_t)(w[1] & 0xffffu)); f[3] = bf2f((ushort_t)(w[1] >> 16));
}
__device__ __forceinline__ u32x2 pk4bf(const float* v) {
    u32x2 pk;
    pk[0] = (uint32)f2bf(v[0]) | ((uint32)f2bf(v[1]) << 16);
    pk[1] = (uint32)f2bf(v[2]) | ((uint32)f2bf(v[3]) << 16);
    return pk;
}

#define BM 128
#define BN 128
#define BK 32
#define LDSH (BM * BK)
#define BIGN (1 << 30)

enum { EPI_BIAS = 0, EPI_BIASR = 1, EPI_SCALE = 2, EPI_BN = 3, EPI_PART = 4 };

struct GP {
    const ushort_t* A; const ushort_t* B; void* Cv; ushort_t* CT;
    const ushort_t* bias; const ushort_t* gamma; const ushort_t* beta;
    const ushort_t* mean; const ushort_t* var; const ushort_t* res;
    long coff, sA, sB, sC;
    int K, lda, ldb, ldc, cnmax, ldT;
    float alpha;
};
struct GP2 { GP g[2]; };
struct VecArgs { const void* s[14]; ushort_t* d[14]; int n[14]; };
struct WtArgs { const void* s[6]; ushort_t* d[6]; int R[6]; int C[6]; };

struct MegaArgs {
    const void* in0; const void* in1;
    ushort_t* det; ushort_t* aim;
    VecArgs va; WtArgs wa;
    GP2 conv, part, ndna, outs;
    const float* P1; const float* P2; ushort_t* G1T; ushort_t* G2T;
    uint32* bar;
};

// per-block dtype sniff: read first 1KB of detect, count non-f32-like exponents
__device__ __forceinline__ bool sniff(const void* in0) {
    const uint32* s = (const uint32*)in0;
    const int lane = threadIdx.x & 63;
    int wd = 0;
    for (int c = 0; c < 4; c++) {
        const uint32 w = s[lane * 4 + c];
        const uint32 e = (w >> 7) & 0xFFu;
        wd += (e < 64u) || (e >= 192u);
    }
    for (int off = 32; off; off >>= 1) wd += __shfl_down(wd, off);
    return __shfl(wd, 0) > 32;
}

// device-wide barrier: all NWG blocks co-resident (guaranteed by launch_bounds +
// 16KB LDS). arrival via device-scope atomicAdd; spin at agent scope with s_sleep.
__device__ void gbar(uint32* ctr) {
    __syncthreads();                 // drains each wave's outstanding mem ops
    if (threadIdx.x == 0) {
        __threadfence();             // release: publish this block's writes
        atomicAdd(ctr, 1u);
        while (__hip_atomic_load(ctr, __ATOMIC_RELAXED, __HIP_MEMORY_SCOPE_AGENT) < NWG)
            __builtin_amdgcn_s_sleep(4);
        __threadfence();             // acquire: invalidate stale cache
    }
    __syncthreads();
}

__device__ __forceinline__ void decode(int bid, int nwg, int gx, int gy,
                                       int ys, int zs,
                                       int& bx, int& by, int& bz, int& sel) {
    const uint32 swz = (uint32)(bid & 7) * (uint32)(nwg >> 3) + (uint32)(bid >> 3);
    bx = (int)(swz % (uint32)gx);
    const uint32 t1 = swz / (uint32)gx;
    by = (int)(t1 % (uint32)gy);
    bz = (int)(t1 / (uint32)gy);
    sel = 0;
    if (by >= ys) { by -= ys; sel = 1; }
    if (bz >= zs) { bz -= zs; sel = 1; }
}

// one canon virtual block: [0,2048) detect copy, [2048,3072) aim copy,
// [3072,4608) weight transpose tiles, 4608 = small vectors
__device__ void canon_vb(const MegaArgs& a, int b, bool isf32, float (*st)[33]) {
    if (b < 3072) {
        const void* src; ushort_t* dst; long n; int b0, nb;
        if (b < 2048) { src = a.in0; dst = a.det; n = 16777216; b0 = b; nb = 2048; }
        else          { src = a.in1; dst = a.aim; n = 4194304;  b0 = b - 2048; nb = 1024; }
        long i = ((long)b0 * 256 + threadIdx.x) * 8;
        const long stride = (long)nb * 256 * 8;
        if (isf32) {
            const float* s = (const float*)src;
            for (; i < n; i += stride) {
                const f32x4 x = *(const f32x4*)(s + i);
                const f32x4 y = *(const f32x4*)(s + i + 4);
                u32x4 o;
                o[0] = (uint32)f2bf(x[0]) | ((uint32)f2bf(x[1]) << 16);
                o[1] = (uint32)f2bf(x[2]) | ((uint32)f2bf(x[3]) << 16);
                o[2] = (uint32)f2bf(y[0]) | ((uint32)f2bf(y[1]) << 16);
                o[3] = (uint32)f2bf(y[2]) | ((uint32)f2bf(y[3]) << 16);
                *(u32x4*)(dst + i) = o;
            }
        } else {
            const ushort_t* s = (const ushort_t*)src;
            for (; i < n; i += stride)
                *(u32x4*)(dst + i) = *(const u32x4*)(s + i);
        }
    } else if (b < 4608) {
        const int local = b - 3072;
        const int wsel = local >> 8;
        const int rem = local & 255;
        const int tr = rem >> 4, tc = rem & 15;
        const int R = a.wa.R[wsel], C = a.wa.C[wsel];
        if (tc * 32 < C && tr * 32 < R) {        // block-uniform (no return!)
            const int t = threadIdx.x;
            const int r = t >> 3, c4 = (t & 7) * 4;
            const long sbase = (long)(tr * 32 + r) * C + tc * 32 + c4;
            if (isf32) {
                const float* S = (const float*)a.wa.s[wsel];
                const f32x4 v = *(const f32x4*)(S + sbase);
                for (int u = 0; u < 4; u++) st[r][c4 + u] = v[u];
            } else {
                const ushort_t* S = (const ushort_t*)a.wa.s[wsel];
                for (int u = 0; u < 4; u++) st[r][c4 + u] = bf2f(S[sbase + u]);
            }
            __syncthreads();
            float tv[4];
            for (int u = 0; u < 4; u++) tv[u] = st[c4 + u][r];
            *(u32x2*)(a.wa.d[wsel] + (long)(tc * 32 + r) * R + tr * 32 + c4) = pk4bf(tv);
        }
    } else {
        const int t = threadIdx.x;
        for (int seg = 0; seg < 14; seg++) {
            const int n = a.va.n[seg];
            if (isf32) {
                const float* s = (const float*)a.va.s[seg];
                for (int i = t; i < n; i += 256) a.va.d[seg][i] = f2bf(s[i]);
            } else {
                const ushort_t* s = (const ushort_t*)a.va.s[seg];
                for (int i = t; i < n; i += 256) a.va.d[seg][i] = s[i];
            }
        }
    }
}

// reduce 8 fp32 split-K partials + transposed bf16 store (1024 tiles)
__device__ void reduce_tile(const MegaArgs& a, int bid, float (*st)[33]) {
    const int tn = bid & 7, tm = (bid >> 3) & 7, zz = bid >> 6;
    const float* P = (zz < 8) ? a.P1 : a.P2;
    ushort_t* out  = (zz < 8) ? a.G1T : a.G2T;
    const int b = zz & 7;
    const int t = threadIdx.x;
    const int r = t >> 3, c4 = (t & 7) * 4;
    const float* base = P + (long)b * 8 * 65536 + (long)(tm * 32 + r) * 256 + tn * 32 + c4;
    f32x4 acc = {0.f, 0.f, 0.f, 0.f};
    for (int kc = 0; kc < 8; kc++) acc += *(const f32x4*)(base + (long)kc * 65536);
    for (int u = 0; u < 4; u++) st[r][c4 + u] = acc[u];
    __syncthreads();
    float tv[4];
    for (int u = 0; u < 4; u++) tv[u] = st[c4 + u][r];
    *(u32x2*)(out + (long)b * 65536 + (long)(tn * 32 + r) * 256 + tm * 32 + c4) = pk4bf(tv);
}

// NT GEMM tile: C[m][n] = sum_k A[m][k]*B[n][k]. 1-phase global_load_lds staging
// (16B/lane, pre-swizzled source so XOR'd ds_read_b128 frags are conflict-light).
template <int EPI, bool DYNOUT, bool DUALT, bool SWAP>
__device__ void gemm_tile(const GP& p, int bx, int by, int bz,
                          ushort_t* Asb, ushort_t* Bsb, bool isf32) {
    const ushort_t* A = p.A + (long)bz * p.sA;
    const ushort_t* B = p.B + (long)bz * p.sB;
    const long cbase = p.coff + (long)bz * p.sC;
    const int lda = p.lda, ldb = p.ldb, ldc = p.ldc, K = p.K;

    const int tid  = threadIdx.x;
    const int lane = tid & 63;
    const int w    = tid >> 6;
    const int wr   = w >> 1, wc = w & 1;
    const int lr   = lane & 15, q = lane >> 4;

    const int m0 = by * BM;
    const int n0 = bx * BN;

    const int lrow = lane >> 2, lu = lane & 3;
    const int us = (lu ^ ((lrow >> 1) & 3)) * 8;          // source-side swizzle
    const int ra0 = w * 32 + lrow, ra1 = w * 32 + 16 + lrow;
    const ushort_t* Ar0 = A + (long)(m0 + ra0) * lda + us;
    const ushort_t* Ar1 = A + (long)(m0 + ra1) * lda + us;
    const ushort_t* Br0 = B + (long)(n0 + ra0) * ldb + us;
    const ushort_t* Br1 = B + (long)(n0 + ra1) * ldb + us;
    ushort_t* sA0 = Asb + (w * 2 + 0) * 512;
    ushort_t* sA1 = Asb + (w * 2 + 1) * 512;
    ushort_t* sB0 = Bsb + (w * 2 + 0) * 512;
    ushort_t* sB1 = Bsb + (w * 2 + 1) * 512;

    const int swq = (q ^ ((lr >> 1) & 3)) * 8;            // read-side swizzle

    f32x4 acc[4][4];
#pragma unroll
    for (int i = 0; i < 4; i++)
#pragma unroll
        for (int j = 0; j < 4; j++) acc[i][j] = (f32x4){0.f, 0.f, 0.f, 0.f};

    for (int k0 = 0; k0 < K; k0 += BK) {
        gl_lds16(Ar0 + k0, sA0); gl_lds16(Ar1 + k0, sA1);
        gl_lds16(Br0 + k0, sB0); gl_lds16(Br1 + k0, sB1);
        __syncthreads();

        bf16x8 af[4], bfr[4];
#pragma unroll
        for (int i = 0; i < 4; i++)
            af[i] = __builtin_bit_cast(bf16x8,
                *(const u32x4*)(&Asb[(wr * 64 + i * 16 + lr) * BK + swq]));
#pragma unroll
        for (int j = 0; j < 4; j++)
            bfr[j] = __builtin_bit_cast(bf16x8,
                *(const u32x4*)(&Bsb[(wc * 64 + j * 16 + lr) * BK + swq]));
#pragma unroll
        for (int i = 0; i < 4; i++)
#pragma unroll
            for (int j = 0; j < 4; j++) {
                if constexpr (SWAP)
                    acc[i][j] = __builtin_amdgcn_mfma_f32_16x16x32_bf16(bfr[j], af[i], acc[i][j], 0, 0, 0);
                else
                    acc[i][j] = __builtin_amdgcn_mfma_f32_16x16x32_bf16(af[i], bfr[j], acc[i][j], 0, 0, 0);
            }
        __syncthreads();
    }

    if constexpr (SWAP) {
#pragma unroll
        for (int j = 0; j < 4; j++) {
            const int coln = n0 + wc * 64 + j * 16 + q * 4;
            float sc4[4], sh4[4];
            if constexpr (EPI == EPI_BIAS) {
                float bb[4]; ld4bf(p.bias + coln, bb);
#pragma unroll
                for (int r = 0; r < 4; r++) { sc4[r] = 1.f; sh4[r] = bb[r]; }
            } else if constexpr (EPI == EPI_SCALE) {
#pragma unroll
                for (int r = 0; r < 4; r++) { sc4[r] = p.alpha; sh4[r] = 0.f; }
            } else if constexpr (EPI == EPI_BN) {
                float bb[4], g[4], bt[4], mn[4], vr[4];
                ld4bf(p.bias + coln, bb); ld4bf(p.gamma + coln, g); ld4bf(p.beta + coln, bt);
                ld4bf(p.mean + coln, mn); ld4bf(p.var + coln, vr);
#pragma unroll
                for (int r = 0; r < 4; r++) {
                    const float s = g[r] * rsqrtf(vr[r] + 1e-3f);
                    sc4[r] = s;
                    sh4[r] = s * bb[r] + bt[r] - s * mn[r];
                }
            }
#pragma unroll
            for (int i = 0; i < 4; i++) {
                const int row = m0 + wr * 64 + i * 16 + lr;
                const long off = cbase + (long)row * ldc + coln;
                float v[4];
#pragma unroll
                for (int r = 0; r < 4; r++) v[r] = acc[i][j][r];
                if constexpr (EPI == EPI_BIASR) {
                    const float bs = bf2f(p.bias[row]);
#pragma unroll
                    for (int r = 0; r < 4; r++) v[r] += bs;
                } else if constexpr (EPI == EPI_BN) {
                    float rs[4]; ld4bf(p.res + (long)row * ldc + coln, rs);
#pragma unroll
                    for (int r = 0; r < 4; r++) v[r] = sc4[r] * v[r] + sh4[r] + rs[r];
                } else if constexpr (EPI != EPI_PART) {
#pragma unroll
                    for (int r = 0; r < 4; r++) v[r] = sc4[r] * v[r] + sh4[r];
                }
                if constexpr (EPI == EPI_PART) {
                    *(f32x4*)((float*)p.Cv + off) = (f32x4){v[0], v[1], v[2], v[3]};
                } else if constexpr (DYNOUT) {
                    if (isf32) *(f32x4*)((float*)p.Cv + off) = (f32x4){v[0], v[1], v[2], v[3]};
                    else       *(u32x2*)((ushort_t*)p.Cv + off) = pk4bf(v);
                } else {
                    *(u32x2*)((ushort_t*)p.Cv + off) = pk4bf(v);
                }
            }
        }
    } else {
        const bool doC = (n0 < p.cnmax);
#pragma unroll
        for (int j = 0; j < 4; j++) {
            const int col = n0 + wc * 64 + j * 16 + lr;
            float bs = 0.f, sc = 1.f, sh = 0.f;
            if constexpr (EPI == EPI_BIAS || EPI == EPI_BN) bs = bf2f(p.bias[col]);
            if constexpr (EPI == EPI_BN) {
                const float g  = bf2f(p.gamma[col]);
                const float bt = bf2f(p.beta[col]);
                const float mn = bf2f(p.mean[col]);
                const float vr = bf2f(p.var[col]);
                sc = g * rsqrtf(vr + 1e-3f);
                sh = bt - sc * mn;
            }
#pragma unroll
            for (int i = 0; i < 4; i++) {
                const int rowbase = m0 + wr * 64 + i * 16 + q * 4;
                ushort_t tmp[4];
#pragma unroll
                for (int r = 0; r < 4; r++) {
                    const int row = rowbase + r;
                    float v = acc[i][j][r];
                    if constexpr (EPI == EPI_BIAS) v += bs;
                    else if constexpr (EPI == EPI_BIASR) v += bf2f(p.bias[row]);
                    else if constexpr (EPI == EPI_SCALE) v *= p.alpha;
                    else if constexpr (EPI == EPI_BN)
                        v = sc * (v + bs) + sh + bf2f(p.res[(long)row * ldc + col]);
                    const long off = cbase + (long)row * ldc + col;
                    if constexpr (EPI == EPI_PART) {
                        ((float*)p.Cv)[off] = v;
                    } else if constexpr (DYNOUT) {
                        if (isf32) ((float*)p.Cv)[off] = v;
                        else       ((ushort_t*)p.Cv)[off] = f2bf(v);
                    } else {
                        const ushort_t us2 = f2bf(v);
                        tmp[r] = us2;
                        if (doC) ((ushort_t*)p.Cv)[off] = us2;
                    }
                }
                if constexpr (DUALT) {
                    u32x2 pk;
                    pk[0] = (uint32)tmp[0] | ((uint32)tmp[1] << 16);
                    pk[1] = (uint32)tmp[2] | ((uint32)tmp[3] << 16);
                    *(u32x2*)(p.CT + (long)col * p.ldT + rowbase) = pk;
                }
            }
        }
    }
}

// ONE persistent kernel: 6 phases with device-wide barriers between.
// NWG=1280 blocks = exactly 5/CU; launch_bounds(256,5) caps VGPR<=102 so all
// blocks are guaranteed co-resident (LDS 16KB -> 10/CU; wave slots -> 8/CU).
__global__ __launch_bounds__(256, 5) void mega(MegaArgs a) {
    __shared__ __align__(16) ushort_t As[LDSH];
    __shared__ __align__(16) ushort_t Bs[LDSH];
    float (*st)[33] = (float(*)[33])As;   // canon/reduce reuse (4.2KB <= 8KB)

    const bool isf32 = sniff(a.in0);
    const int bid = blockIdx.x;
    int bx, by, bz, sel;

    // P0: canonicalization (activations, weights-T, small vectors)
    for (int vb = bid; vb < 4609; vb += NWG) {
        canon_vb(a, vb, isf32, st);
        __syncthreads();
    }
    gbar(a.bar + 0);

    // P1: merged convs (1280 tiles 1:1): phi/theta + phiT/d_xT + thetaT/a_xT
    decode(bid, 1280, 4, 320, 256, BIGN, bx, by, bz, sel);
    gemm_tile<EPI_BIAS, false, true, false>(a.conv.g[sel], bx, by, bz, As, Bs, isf32);
    gbar(a.bar + 1);

    // P2: split-K partials (512 tiles)
    if (bid < 512) {
        decode(bid, 512, 2, 2, BIGN, 64, bx, by, bz, sel);
        gemm_tile<EPI_PART, false, false, true>(a.part.g[sel], bx, by, bz, As, Bs, isf32);
    }
    gbar(a.bar + 2);

    // P3: reduce partials -> G1T/G2T (1024 tiles)
    if (bid < 1024) reduce_tile(a, bid, st);
    gbar(a.bar + 3);

    // P4: nd/na (640 tiles)
    if (bid < 640) {
        decode(bid, 640, 2, 40, 32, BIGN, bx, by, bz, sel);
        gemm_tile<EPI_SCALE, false, false, true>(a.ndna.g[sel], bx, by, bz, As, Bs, isf32);
    }
    gbar(a.bar + 4);

    // P5: BN outputs + residual (1280 tiles 1:1)
    decode(bid, 1280, 4, 320, 256, BIGN, bx, by, bz, sel);
    gemm_tile<EPI_BN, true, false, true>(a.outs.g[sel], bx, by, bz, As, Bs, isf32);
}

extern "C" void kernel_launch(void* const* d_in, const int* in_sizes, int n_in,
                              void* d_out, int out_size, void* d_ws, size_t ws_size,
                              hipStream_t stream)
{
    uint32* bar = (uint32*)d_ws;
    ushort_t* base = (ushort_t*)((char*)d_ws + 256);
    long o = 0;
    ushort_t* detect_c = base + o; o += 16777216;   // [32768][512]
    ushort_t* aim_c    = base + o; o += 4194304;    // [8192][512]
    ushort_t* WpgT = base + o; o += 262144;         // [512][512] = [WpT; WgT]
    ushort_t* WtgT = base + o; o += 262144;         // [512][512] = [WtT; WgT]
    ushort_t* WwT  = base + o; o += 131072;         // [512][256]
    ushort_t* WqT  = base + o; o += 131072;
    ushort_t* bpg_c  = base + o; o += 512;          // [bp; bg]
    ushort_t* btg_c  = base + o; o += 512;          // [bt; bg]
    ushort_t* bw_c   = base + o; o += 512;
    ushort_t* gw_c   = base + o; o += 512;
    ushort_t* betw_c = base + o; o += 512;
    ushort_t* mw_c   = base + o; o += 512;
    ushort_t* vw_c   = base + o; o += 512;
    ushort_t* bq_c   = base + o; o += 512;
    ushort_t* gq_c   = base + o; o += 512;
    ushort_t* betq_c = base + o; o += 512;
    ushort_t* mq_c   = base + o; o += 512;
    ushort_t* vq_c   = base + o; o += 512;
    ushort_t* phi    = base + o; o += 8388608;      // [32768][256]
    ushort_t* PT     = base + o; o += 16777216;     // [512][32768]: phiT rows 0-255, d_xT 256-511
    ushort_t* theta  = base + o; o += 2097152;      // [8192][256]
    ushort_t* TT     = base + o; o += 4194304;      // [512][8192]: thetaT + a_xT
    ushort_t* G1T    = base + o; o += 524288;       // [8][256][256]
    ushort_t* G2T    = base + o; o += 524288;
    ushort_t* U      = base + o; o += 16777216;     // union: P1,P2 then na,nd
    float* P1 = (float*)U;
    float* P2 = P1 + 4194304;
    ushort_t* na = U;
    ushort_t* nd = na + 2097152;
    ushort_t* phiT = PT;
    ushort_t* d_xT = PT + 8388608;
    ushort_t* thetaT = TT;
    ushort_t* a_xT = TT + 2097152;

    hipMemsetAsync(bar, 0, 64, stream);   // zero the 5 barrier counters

    MegaArgs ma;
    ma.in0 = d_in[0]; ma.in1 = d_in[1];
    ma.det = detect_c; ma.aim = aim_c;
    ma.P1 = P1; ma.P2 = P2; ma.G1T = G1T; ma.G2T = G2T;
    ma.bar = bar;

    const int vidx[14] = {7, 3, 5, 3, 9, 10, 11, 12, 13, 15, 16, 17, 18, 19};
    ushort_t* vdst[14] = {bpg_c, bpg_c + 256, btg_c, btg_c + 256,
                          bw_c, gw_c, betw_c, mw_c, vw_c,
                          bq_c, gq_c, betq_c, mq_c, vq_c};
    const int vn[14] = {256, 256, 256, 256, 512, 512, 512, 512, 512, 512, 512, 512, 512, 512};
    for (int i = 0; i < 14; i++) { ma.va.s[i] = d_in[vidx[i]]; ma.va.d[i] = vdst[i]; ma.va.n[i] = vn[i]; }

    ma.wa.s[0] = d_in[6];  ma.wa.d[0] = WpgT;             ma.wa.R[0] = 512; ma.wa.C[0] = 256;
    ma.wa.s[1] = d_in[2];  ma.wa.d[1] = WpgT + 256 * 512; ma.wa.R[1] = 512; ma.wa.C[1] = 256;
    ma.wa.s[2] = d_in[4];  ma.wa.d[2] = WtgT;             ma.wa.R[2] = 512; ma.wa.C[2] = 256;
    ma.wa.s[3] = d_in[2];  ma.wa.d[3] = WtgT + 256 * 512; ma.wa.R[3] = 512; ma.wa.C[3] = 256;
    ma.wa.s[4] = d_in[8];  ma.wa.d[4] = WwT;              ma.wa.R[4] = 256; ma.wa.C[4] = 512;
    ma.wa.s[5] = d_in[14]; ma.wa.d[5] = WqT;              ma.wa.R[5] = 256; ma.wa.C[5] = 512;

    const ushort_t* np = nullptr;
    ushort_t* npm = nullptr;

    ma.conv.g[0] = GP{detect_c, WpgT, phi, PT, bpg_c, np, np, np, np, np,
                      0, 0, 0, 0, 512, 512, 512, 256, 256, 32768, 1.f};
    ma.conv.g[1] = GP{aim_c, WtgT, theta, TT, btg_c, np, np, np, np, np,
                      0, 0, 0, 0, 512, 512, 512, 256, 256, 8192, 1.f};

    ma.part.g[0] = GP{phiT, d_xT, P1, npm, np, np, np, np, np, np,
                      0, 512, 512, 65536, 512, 32768, 32768, 256, BIGN, 0, 1.f};
    ma.part.g[1] = GP{thetaT, a_xT, P2, npm, np, np, np, np, np, np,
                      0, 128, 128, 65536, 128, 8192, 8192, 256, BIGN, 0, 1.f};

    ma.ndna.g[0] = GP{phi, G2T, nd, npm, np, np, np, np, np, np,
                      0, 1048576, 65536, 1048576, 256, 256, 256, 256, BIGN, 0, 1.f / 1024.f};
    ma.ndna.g[1] = GP{theta, G1T, na, npm, np, np, np, np, np, np,
                      0, 262144, 65536, 262144, 256, 256, 256, 256, BIGN, 0, 1.f / 4096.f};

    ma.outs.g[0] = GP{nd, WqT, d_out, npm, bq_c, gq_c, betq_c, mq_c, vq_c, detect_c,
                      8192L * 512, 0, 0, 0, 256, 256, 256, 512, BIGN, 0, 1.f};
    ma.outs.g[1] = GP{na, WwT, d_out, npm, bw_c, gw_c, betw_c, mw_c, vw_c, aim_c,
                      0, 0, 0, 0, 256, 256, 256, 512, BIGN, 0, 1.f};

    mega<<<NWG, 256, 0, stream>>>(ma);
}

// Round 8
// 400.821 us; speedup vs baseline: 2.8358x; 2.8358x over previous
//
#include <hip/hip_runtime.h>

typedef unsigned short ushort_t;
typedef unsigned int uint32;
typedef __bf16 bf16x8 __attribute__((ext_vector_type(8)));
typedef float f32x4 __attribute__((ext_vector_type(4)));
typedef uint32 u32x4 __attribute__((ext_vector_type(4)));
typedef uint32 u32x2 __attribute__((ext_vector_type(2)));

typedef __attribute__((address_space(3))) uint32 as3_u32;
typedef const __attribute__((address_space(1))) uint32 as1_u32c;

// async global->LDS, 16B per lane; LDS dest = wave-uniform base + lane*16
__device__ __forceinline__ void gl_lds16(const ushort_t* g, ushort_t* l) {
    __builtin_amdgcn_global_load_lds((as1_u32c*)g, (as3_u32*)l, 16, 0, 0);
}

__device__ __forceinline__ float bf2f(ushort_t u) {
    uint32 x = ((uint32)u) << 16;
    return __builtin_bit_cast(float, x);
}
__device__ __forceinline__ ushort_t f2bf(float f) {
    uint32 x = __builtin_bit_cast(uint32, f);
    x += 0x7fffu + ((x >> 16) & 1u);   // RNE
    return (ushort_t)(x >> 16);
}
__device__ __forceinline__ void ld4bf(const ushort_t* p, float* f) {
    const u32x2 w = *(const u32x2*)p;
    f[0] = bf2f((ushort_t)(w[0] & 0xffffu)); f[1] = bf2f((ushort_t)(w[0] >> 16));
    f[2] = bf2f((ushort_t)(w[1] & 0xffffu)); f[3] = bf2f((ushort_t)(w[1] >> 16));
}
__device__ __forceinline__ u32x2 pk4bf(const float* v) {
    u32x2 pk;
    pk[0] = (uint32)f2bf(v[0]) | ((uint32)f2bf(v[1]) << 16);
    pk[1] = (uint32)f2bf(v[2]) | ((uint32)f2bf(v[3]) << 16);
    return pk;
}

// fused dtype-sniff + small-vector canon
struct VecArgs { const void* s[14]; ushort_t* d[14]; int n[14]; };
__global__ void sniff_vec_kernel(const uint32* __restrict__ src, int* __restrict__ flag,
                                 VecArgs a) {
    __shared__ int cnt;
    if (threadIdx.x == 0) cnt = 0;
    __syncthreads();
    if (threadIdx.x < 64) {
        int weird = 0;
        for (int c = 0; c < 4; c++) {
            uint32 w = src[threadIdx.x * 4 + c];
            uint32 e = (w >> 7) & 0xFFu;
            weird += (e < 64u) || (e >= 192u);
        }
        if (weird) atomicAdd(&cnt, weird);
    }
    __syncthreads();
    const bool isf32 = (cnt > 32);
    if (threadIdx.x == 0) *flag = isf32 ? 1 : 0;
    const int t = threadIdx.x;
    for (int seg = 0; seg < 14; seg++) {
        const int n = a.n[seg];
        if (isf32) {
            const float* s = (const float*)a.s[seg];
            for (int i = t; i < n; i += 256) a.d[seg][i] = f2bf(s[i]);
        } else {
            const ushort_t* s = (const ushort_t*)a.s[seg];
            for (int i = t; i < n; i += 256) a.d[seg][i] = s[i];
        }
    }
}

// all remaining canon work in ONE launch
struct WtArgs { const void* s[6]; ushort_t* d[6]; int R[6]; int C[6]; };
__global__ void canon_all(const void* __restrict__ dsrc, ushort_t* __restrict__ ddst,
                          const void* __restrict__ asrc, ushort_t* __restrict__ adst,
                          WtArgs wa, const int* __restrict__ flag) {
    const bool isf32 = (*flag != 0);
    const int b = blockIdx.x;
    if (b < 3072) {
        const void* src; ushort_t* dst; long n; int b0, nb;
        if (b < 2048) { src = dsrc; dst = ddst; n = 16777216; b0 = b; nb = 2048; }
        else          { src = asrc; dst = adst; n = 4194304;  b0 = b - 2048; nb = 1024; }
        long i = ((long)b0 * 256 + threadIdx.x) * 8;
        const long stride = (long)nb * 256 * 8;
        if (isf32) {
            const float* s = (const float*)src;
            for (; i < n; i += stride) {
                const f32x4 a = *(const f32x4*)(s + i);
                const f32x4 c = *(const f32x4*)(s + i + 4);
                u32x4 o;
                o[0] = (uint32)f2bf(a[0]) | ((uint32)f2bf(a[1]) << 16);
                o[1] = (uint32)f2bf(a[2]) | ((uint32)f2bf(a[3]) << 16);
                o[2] = (uint32)f2bf(c[0]) | ((uint32)f2bf(c[1]) << 16);
                o[3] = (uint32)f2bf(c[2]) | ((uint32)f2bf(c[3]) << 16);
                *(u32x4*)(dst + i) = o;
            }
        } else {
            const ushort_t* s = (const ushort_t*)src;
            for (; i < n; i += stride)
                *(u32x4*)(dst + i) = *(const u32x4*)(s + i);
        }
    } else {
        const int local = b - 3072;
        const int wsel = local >> 8;
        const int rem = local & 255;
        const int tr = rem >> 4, tc = rem & 15;
        const int R = wa.R[wsel], C = wa.C[wsel];
        if (tc * 32 >= C || tr * 32 >= R) return;
        __shared__ float s[32][33];
        const int t = threadIdx.x;
        const int r = t >> 3, c4 = (t & 7) * 4;
        const long sbase = (long)(tr * 32 + r) * C + tc * 32 + c4;
        if (isf32) {
            const float* S = (const float*)wa.s[wsel];
            const f32x4 v = *(const f32x4*)(S + sbase);
            for (int u = 0; u < 4; u++) s[r][c4 + u] = v[u];
        } else {
            const ushort_t* S = (const ushort_t*)wa.s[wsel];
            for (int u = 0; u < 4; u++) s[r][c4 + u] = bf2f(S[sbase + u]);
        }
        __syncthreads();
        float tv[4];
        for (int u = 0; u < 4; u++) tv[u] = s[c4 + u][r];
        *(u32x2*)(wa.d[wsel] + (long)(tc * 32 + r) * R + tr * 32 + c4) = pk4bf(tv);
    }
}

// reduce 8 fp32 split-K partials + transposed bf16 store
__global__ void reduce_t2_kernel(const float* __restrict__ P1, const float* __restrict__ P2,
                                 ushort_t* __restrict__ G1T, ushort_t* __restrict__ G2T) {
    __shared__ float s[32][33];
    const int zz = blockIdx.z;
    const float* P = (zz < 8) ? P1 : P2;
    ushort_t* out  = (zz < 8) ? G1T : G2T;
    const int b = zz & 7;
    const int tm = blockIdx.y, tn = blockIdx.x;
    const int t = threadIdx.x;
    const int r = t >> 3, c4 = (t & 7) * 4;
    const float* base = P + (long)b * 8 * 65536 + (long)(tm * 32 + r) * 256 + tn * 32 + c4;
    f32x4 acc = {0.f, 0.f, 0.f, 0.f};
    for (int kc = 0; kc < 8; kc++) acc += *(const f32x4*)(base + (long)kc * 65536);
    for (int u = 0; u < 4; u++) s[r][c4 + u] = acc[u];
    __syncthreads();
    float tv[4];
    for (int u = 0; u < 4; u++) tv[u] = s[c4 + u][r];
    *(u32x2*)(out + (long)b * 65536 + (long)(tn * 32 + r) * 256 + tm * 32 + c4) = pk4bf(tv);
}

#define BM 128
#define BN 128
#define BK 32
#define LDSH (BM * BK)
#define NBUF 3
#define BIGN (1 << 30)

enum { EPI_BIAS = 0, EPI_BIASR = 1, EPI_SCALE = 2, EPI_BN = 3, EPI_PART = 4 };

struct GP {
    const ushort_t* A; const ushort_t* B; void* Cv; ushort_t* CT;
    const ushort_t* bias; const ushort_t* gamma; const ushort_t* beta;
    const ushort_t* mean; const ushort_t* var; const ushort_t* res;
    long coff, sA, sB, sC;
    int K, lda, ldb, ldc, cnmax, ldT;
    float alpha;
};
struct GP2 { GP g[2]; };

// NT GEMM (r6-proven): depth-3 rotating LDS pipeline, one barrier per K-step.
template <int EPI, bool DYNOUT, bool DUALT, bool SWAP>
__global__ __launch_bounds__(256) void gemm_nt(GP2 ga, int ysplit, int zsplit,
                                               const int* __restrict__ flag)
{
    __shared__ __align__(16) ushort_t As[NBUF * LDSH];
    __shared__ __align__(16) ushort_t Bs[NBUF * LDSH];

    const bool isf32 = DYNOUT ? (*flag != 0) : false;

    const uint32 gx = gridDim.x, gy = gridDim.y;
    const uint32 nwg = gx * gy * gridDim.z;
    const uint32 lid = blockIdx.x + gx * (blockIdx.y + gy * blockIdx.z);
    const uint32 swz = (lid & 7u) * (nwg >> 3) + (lid >> 3);
    const uint32 bx = swz % gx, t1 = swz / gx;
    int by = (int)(t1 % gy), bz = (int)(t1 / gy);

    int sel = 0;
    if (by >= ysplit) { by -= ysplit; sel = 1; }
    if (bz >= zsplit) { bz -= zsplit; sel = 1; }
    const GP& p = ga.g[sel];

    const ushort_t* A = p.A + (long)bz * p.sA;
    const ushort_t* B = p.B + (long)bz * p.sB;
    const long cbase = p.coff + (long)bz * p.sC;
    const int lda = p.lda, ldb = p.ldb, ldc = p.ldc, K = p.K;

    const int tid  = threadIdx.x;
    const int lane = tid & 63;
    const int w    = tid >> 6;
    const int wr   = w >> 1, wc = w & 1;
    const int lr   = lane & 15, q = lane >> 4;

    const int m0 = by * BM;
    const int n0 = bx * BN;

    const int lrow = lane >> 2, lu = lane & 3;
    const int us = (lu ^ ((lrow >> 1) & 3)) * 8;
    const int ra0 = w * 32 + lrow, ra1 = w * 32 + 16 + lrow;
    const ushort_t* Ar0 = A + (long)(m0 + ra0) * lda + us;
    const ushort_t* Ar1 = A + (long)(m0 + ra1) * lda + us;
    const ushort_t* Br0 = B + (long)(n0 + ra0) * ldb + us;
    const ushort_t* Br1 = B + (long)(n0 + ra1) * ldb + us;
    ushort_t* sA0 = &As[(w * 2 + 0) * 512];
    ushort_t* sA1 = &As[(w * 2 + 1) * 512];
    ushort_t* sB0 = &Bs[(w * 2 + 0) * 512];
    ushort_t* sB1 = &Bs[(w * 2 + 1) * 512];

    const int swq = (q ^ ((lr >> 1) & 3)) * 8;

    f32x4 acc[4][4];
#pragma unroll
    for (int i = 0; i < 4; i++)
#pragma unroll
        for (int j = 0; j < 4; j++) acc[i][j] = (f32x4){0.f, 0.f, 0.f, 0.f};

    const int nt = K / BK;
    {
        gl_lds16(Ar0, sA0); gl_lds16(Ar1, sA1);
        gl_lds16(Br0, sB0); gl_lds16(Br1, sB1);
        if (nt > 1) {
            gl_lds16(Ar0 + BK, sA0 + LDSH); gl_lds16(Ar1 + BK, sA1 + LDSH);
            gl_lds16(Br0 + BK, sB0 + LDSH); gl_lds16(Br1 + BK, sB1 + LDSH);
        }
    }

    int c0 = 0, c2 = 2;
    for (int t = 0; t < nt; ++t) {
        if (t + 1 < nt) asm volatile("s_waitcnt vmcnt(4)" ::: "memory");
        else            asm volatile("s_waitcnt vmcnt(0)" ::: "memory");
        __builtin_amdgcn_s_barrier();
        __builtin_amdgcn_sched_barrier(0);

        if (t + 2 < nt) {
            const int nb = c2 * LDSH;
            const int kn = (t + 2) * BK;
            gl_lds16(Ar0 + kn, sA0 + nb); gl_lds16(Ar1 + kn, sA1 + nb);
            gl_lds16(Br0 + kn, sB0 + nb); gl_lds16(Br1 + kn, sB1 + nb);
        }
        __builtin_amdgcn_sched_barrier(0);

        const ushort_t* Ab = As + c0 * LDSH;
        const ushort_t* Bb = Bs + c0 * LDSH;
        bf16x8 af[4], bfr[4];
#pragma unroll
        for (int i = 0; i < 4; i++)
            af[i] = __builtin_bit_cast(bf16x8,
                *(const u32x4*)(&Ab[(wr * 64 + i * 16 + lr) * BK + swq]));
#pragma unroll
        for (int j = 0; j < 4; j++)
            bfr[j] = __builtin_bit_cast(bf16x8,
                *(const u32x4*)(&Bb[(wc * 64 + j * 16 + lr) * BK + swq]));
#pragma unroll
        for (int i = 0; i < 4; i++)
#pragma unroll
            for (int j = 0; j < 4; j++) {
                if constexpr (SWAP)
                    acc[i][j] = __builtin_amdgcn_mfma_f32_16x16x32_bf16(bfr[j], af[i], acc[i][j], 0, 0, 0);
                else
                    acc[i][j] = __builtin_amdgcn_mfma_f32_16x16x32_bf16(af[i], bfr[j], acc[i][j], 0, 0, 0);
            }
        __builtin_amdgcn_sched_barrier(0);

        c0 = (c0 + 1 == NBUF) ? 0 : c0 + 1;
        c2 = (c2 + 1 == NBUF) ? 0 : c2 + 1;
    }

    if constexpr (SWAP) {
#pragma unroll
        for (int j = 0; j < 4; j++) {
            const int coln = n0 + wc * 64 + j * 16 + q * 4;
#pragma unroll
            for (int i = 0; i < 4; i++) {
                const int row = m0 + wr * 64 + i * 16 + lr;
                const long off = cbase + (long)row * ldc + coln;
                float v[4];
#pragma unroll
                for (int r = 0; r < 4; r++) v[r] = acc[i][j][r];
                if constexpr (EPI == EPI_PART) {
                    *(f32x4*)((float*)p.Cv + off) = (f32x4){v[0], v[1], v[2], v[3]};
                } else if constexpr (DYNOUT) {
                    if (isf32) *(f32x4*)((float*)p.Cv + off) = (f32x4){v[0], v[1], v[2], v[3]};
                    else       *(u32x2*)((ushort_t*)p.Cv + off) = pk4bf(v);
                } else {
                    *(u32x2*)((ushort_t*)p.Cv + off) = pk4bf(v);
                }
            }
        }
    } else {
        const bool doC = (n0 < p.cnmax);
#pragma unroll
        for (int j = 0; j < 4; j++) {
            const int col = n0 + wc * 64 + j * 16 + lr;
            float bs = 0.f;
            if constexpr (EPI == EPI_BIAS) bs = bf2f(p.bias[col]);
#pragma unroll
            for (int i = 0; i < 4; i++) {
                const int rowbase = m0 + wr * 64 + i * 16 + q * 4;
                ushort_t tmp[4];
#pragma unroll
                for (int r = 0; r < 4; r++) {
                    const int row = rowbase + r;
                    float v = acc[i][j][r];
                    if constexpr (EPI == EPI_BIAS) v += bs;
                    else if constexpr (EPI == EPI_BIASR) v += bf2f(p.bias[row]);
                    const long off = cbase + (long)row * ldc + col;
                    if constexpr (EPI == EPI_PART) {
                        ((float*)p.Cv)[off] = v;
                    } else {
                        const ushort_t us2 = f2bf(v);
                        tmp[r] = us2;
                        if (doC) ((ushort_t*)p.Cv)[off] = us2;
                    }
                }
                if constexpr (DUALT) {
                    u32x2 pk;
                    pk[0] = (uint32)tmp[0] | ((uint32)tmp[1] << 16);
                    pk[1] = (uint32)tmp[2] | ((uint32)tmp[3] << 16);
                    *(u32x2*)(p.CT + (long)col * p.ldT + rowbase) = pk;
                }
            }
        }
    }
}

// ---------------- fused nd/na + BN-out kernel ----------------
// Each block owns 128 rows. Phase A: X[128][256] = (act · GT^T)*alpha, computed
// with MFMA fragments loaded DIRECTLY from global (act/GT are L2/L3-hot), result
// packed bf16 into XOR-swizzled LDS. One __syncthreads. Phase B: 4 n-chunks of
// out[128][512] = BN(X·W^T) + res, A-frags from LDS, B-frags direct from global
// (weights tiny, L2-hot). No other barriers; no nd/na global round-trip.
struct FO {
    const ushort_t* act; const ushort_t* GT; const ushort_t* W;
    const ushort_t* bias; const ushort_t* gamma; const ushort_t* beta;
    const ushort_t* mean; const ushort_t* var; const ushort_t* res;
    long coff; int bshift; float alpha;
};
struct FOArgs { FO f[2]; void* out; };

__device__ __forceinline__ uint32 xswz(int row, int colbyte) {
    return (uint32)(row * 512 + colbyte) ^ (uint32)((row & 7) << 4);
}

__global__ __launch_bounds__(256) void fused_out(FOArgs a, const int* __restrict__ flag) {
    __shared__ __align__(16) ushort_t Xs[128 * 256];   // 64 KB
    const bool isf32 = (*flag != 0);

    // XCD-bijective swizzle over 320 blocks
    const uint32 swz = (blockIdx.x & 7u) * 40u + (blockIdx.x >> 3);
    const int sel = (swz >= 256u) ? 1 : 0;
    const int mb = sel ? (int)swz - 256 : (int)swz;
    const FO p = a.f[sel];
    const int b = mb >> p.bshift;
    const ushort_t* A  = p.act + (long)mb * 128 * 256;
    const ushort_t* GT = p.GT + (long)b * 65536;
    const ushort_t* res = p.res + (long)mb * 128 * 512;
    const long cbase = p.coff + (long)mb * 128 * 512;

    const int tid  = threadIdx.x;
    const int lane = tid & 63;
    const int w    = tid >> 6;
    const int wr   = w >> 1, wc = w & 1;
    const int lr   = lane & 15, q = lane >> 4;

    // ---- phase A ----
#pragma unroll
    for (int nh = 0; nh < 2; nh++) {
        const int n0 = nh * 128;
        f32x4 acc[4][4];
#pragma unroll
        for (int i = 0; i < 4; i++)
#pragma unroll
            for (int j = 0; j < 4; j++) acc[i][j] = (f32x4){0.f, 0.f, 0.f, 0.f};

        for (int k0 = 0; k0 < 256; k0 += 32) {
            bf16x8 af[4], bfr[4];
#pragma unroll
            for (int i = 0; i < 4; i++)
                af[i] = __builtin_bit_cast(bf16x8,
                    *(const u32x4*)(A + (long)(wr * 64 + i * 16 + lr) * 256 + k0 + q * 8));
#pragma unroll
            for (int j = 0; j < 4; j++)
                bfr[j] = __builtin_bit_cast(bf16x8,
                    *(const u32x4*)(GT + (long)(n0 + wc * 64 + j * 16 + lr) * 256 + k0 + q * 8));
#pragma unroll
            for (int i = 0; i < 4; i++)
#pragma unroll
                for (int j = 0; j < 4; j++)
                    acc[i][j] = __builtin_amdgcn_mfma_f32_16x16x32_bf16(bfr[j], af[i], acc[i][j], 0, 0, 0);
        }
        // pack X (alpha applied) into swizzled LDS
#pragma unroll
        for (int j = 0; j < 4; j++) {
            const int colb = n0 + wc * 64 + j * 16 + q * 4;
#pragma unroll
            for (int i = 0; i < 4; i++) {
                const int row = wr * 64 + i * 16 + lr;
                float v[4];
#pragma unroll
                for (int r = 0; r < 4; r++) v[r] = acc[i][j][r] * p.alpha;
                *(u32x2*)((char*)Xs + xswz(row, colb * 2)) = pk4bf(v);
            }
        }
    }
    __syncthreads();

    // ---- phase B ----
#pragma unroll 1
    for (int nb = 0; nb < 4; nb++) {
        const int n0 = nb * 128;
        f32x4 acc[4][4];
#pragma unroll
        for (int i = 0; i < 4; i++)
#pragma unroll
            for (int j = 0; j < 4; j++) acc[i][j] = (f32x4){0.f, 0.f, 0.f, 0.f};

        for (int k0 = 0; k0 < 256; k0 += 32) {
            bf16x8 af[4], bfr[4];
#pragma unroll
            for (int i = 0; i < 4; i++) {
                const int row = wr * 64 + i * 16 + lr;
                af[i] = __builtin_bit_cast(bf16x8,
                    *(const u32x4*)((char*)Xs + xswz(row, (k0 + q * 8) * 2)));
            }
#pragma unroll
            for (int j = 0; j < 4; j++)
                bfr[j] = __builtin_bit_cast(bf16x8,
                    *(const u32x4*)(p.W + (long)(n0 + wc * 64 + j * 16 + lr) * 256 + k0 + q * 8));
#pragma unroll
            for (int i = 0; i < 4; i++)
#pragma unroll
                for (int j = 0; j < 4; j++)
                    acc[i][j] = __builtin_amdgcn_mfma_f32_16x16x32_bf16(bfr[j], af[i], acc[i][j], 0, 0, 0);
        }

        // BN + residual epilogue (vectorized)
#pragma unroll
        for (int j = 0; j < 4; j++) {
            const int coln = n0 + wc * 64 + j * 16 + q * 4;
            float bb[4], g[4], bt[4], mn[4], vr[4], sc4[4], sh4[4];
            ld4bf(p.bias + coln, bb); ld4bf(p.gamma + coln, g); ld4bf(p.beta + coln, bt);
            ld4bf(p.mean + coln, mn); ld4bf(p.var + coln, vr);
#pragma unroll
            for (int r = 0; r < 4; r++) {
                const float s = g[r] * rsqrtf(vr[r] + 1e-3f);
                sc4[r] = s;
                sh4[r] = s * bb[r] + bt[r] - s * mn[r];
            }
#pragma unroll
            for (int i = 0; i < 4; i++) {
                const int row = wr * 64 + i * 16 + lr;
                const long off = cbase + (long)row * 512 + coln;
                float v[4], rs[4];
                ld4bf(res + (long)row * 512 + coln, rs);
#pragma unroll
                for (int r = 0; r < 4; r++) v[r] = sc4[r] * acc[i][j][r] + sh4[r] + rs[r];
                if (isf32) *(f32x4*)((float*)a.out + off) = (f32x4){v[0], v[1], v[2], v[3]};
                else       *(u32x2*)((ushort_t*)a.out + off) = pk4bf(v);
            }
        }
    }
}

extern "C" void kernel_launch(void* const* d_in, const int* in_sizes, int n_in,
                              void* d_out, int out_size, void* d_ws, size_t ws_size,
                              hipStream_t stream)
{
    int* flag = (int*)d_ws;
    ushort_t* base = (ushort_t*)((char*)d_ws + 16);
    long o = 0;
    ushort_t* detect_c = base + o; o += 16777216;   // [32768][512]
    ushort_t* aim_c    = base + o; o += 4194304;    // [8192][512]
    ushort_t* WpgT = base + o; o += 262144;         // [512][512] = [WpT; WgT]
    ushort_t* WtgT = base + o; o += 262144;         // [512][512] = [WtT; WgT]
    ushort_t* WwT  = base + o; o += 131072;         // [512][256]
    ushort_t* WqT  = base + o; o += 131072;
    ushort_t* bpg_c  = base + o; o += 512;
    ushort_t* btg_c  = base + o; o += 512;
    ushort_t* bw_c   = base + o; o += 512;
    ushort_t* gw_c   = base + o; o += 512;
    ushort_t* betw_c = base + o; o += 512;
    ushort_t* mw_c   = base + o; o += 512;
    ushort_t* vw_c   = base + o; o += 512;
    ushort_t* bq_c   = base + o; o += 512;
    ushort_t* gq_c   = base + o; o += 512;
    ushort_t* betq_c = base + o; o += 512;
    ushort_t* mq_c   = base + o; o += 512;
    ushort_t* vq_c   = base + o; o += 512;
    ushort_t* phi    = base + o; o += 8388608;      // [32768][256]
    ushort_t* PT     = base + o; o += 16777216;     // [512][32768]: phiT + d_xT
    ushort_t* theta  = base + o; o += 2097152;      // [8192][256]
    ushort_t* TT     = base + o; o += 4194304;      // [512][8192]: thetaT + a_xT
    ushort_t* G1T    = base + o; o += 524288;       // [8][256][256]
    ushort_t* G2T    = base + o; o += 524288;
    ushort_t* U      = base + o; o += 16777216;     // P1,P2 fp32 (64 slices each)
    float* P1 = (float*)U;
    float* P2 = P1 + 4194304;
    ushort_t* phiT = PT;
    ushort_t* d_xT = PT + 8388608;
    ushort_t* thetaT = TT;
    ushort_t* a_xT = TT + 2097152;

    VecArgs va;
    const int vidx[14] = {7, 3, 5, 3, 9, 10, 11, 12, 13, 15, 16, 17, 18, 19};
    ushort_t* vdst[14] = {bpg_c, bpg_c + 256, btg_c, btg_c + 256,
                          bw_c, gw_c, betw_c, mw_c, vw_c,
                          bq_c, gq_c, betq_c, mq_c, vq_c};
    const int vn[14] = {256, 256, 256, 256, 512, 512, 512, 512, 512, 512, 512, 512, 512, 512};
    for (int i = 0; i < 14; i++) { va.s[i] = d_in[vidx[i]]; va.d[i] = vdst[i]; va.n[i] = vn[i]; }
    sniff_vec_kernel<<<1, 256, 0, stream>>>((const uint32*)d_in[0], flag, va);

    WtArgs wa;
    wa.s[0] = d_in[6];  wa.d[0] = WpgT;              wa.R[0] = 512; wa.C[0] = 256;
    wa.s[1] = d_in[2];  wa.d[1] = WpgT + 256 * 512;  wa.R[1] = 512; wa.C[1] = 256;
    wa.s[2] = d_in[4];  wa.d[2] = WtgT;              wa.R[2] = 512; wa.C[2] = 256;
    wa.s[3] = d_in[2];  wa.d[3] = WtgT + 256 * 512;  wa.R[3] = 512; wa.C[3] = 256;
    wa.s[4] = d_in[8];  wa.d[4] = WwT;               wa.R[4] = 256; wa.C[4] = 512;
    wa.s[5] = d_in[14]; wa.d[5] = WqT;               wa.R[5] = 256; wa.C[5] = 512;
    canon_all<<<4608, 256, 0, stream>>>(d_in[0], detect_c, d_in[1], aim_c, wa, flag);

    const dim3 blk(256);
    const ushort_t* np = nullptr;
    ushort_t* npm = nullptr;

    // merged convs: phi/theta + phiT/d_xT + thetaT/a_xT (one read of each act)
    {
        GP2 g;
        g.g[0] = GP{detect_c, WpgT, phi, PT, bpg_c, np, np, np, np, np,
                    0, 0, 0, 0, 512, 512, 512, 256, 256, 32768, 1.f};
        g.g[1] = GP{aim_c, WtgT, theta, TT, btg_c, np, np, np, np, np,
                    0, 0, 0, 0, 512, 512, 512, 256, 256, 8192, 1.f};
        gemm_nt<EPI_BIAS, false, true, false><<<dim3(4, 320, 1), blk, 0, stream>>>(
            g, 256, BIGN, flag);
    }

    // merged split-K partials: G1 (bz<64, K-chunk 512) + G2 (K-chunk 128)
    {
        GP2 g;
        g.g[0] = GP{phiT, d_xT, P1, npm, np, np, np, np, np, np,
                    0, 512, 512, 65536, 512, 32768, 32768, 256, BIGN, 0, 1.f};
        g.g[1] = GP{thetaT, a_xT, P2, npm, np, np, np, np, np, np,
                    0, 128, 128, 65536, 128, 8192, 8192, 256, BIGN, 0, 1.f};
        gemm_nt<EPI_PART, false, false, true><<<dim3(2, 2, 128), blk, 0, stream>>>(
            g, BIGN, 64, flag);
    }

    reduce_t2_kernel<<<dim3(8, 8, 16), blk, 0, stream>>>(P1, P2, G1T, G2T);

    // fused nd/na + BN outputs: 320 blocks (256 out1 + 64 out0)
    {
        FOArgs fa;
        fa.out = d_out;
        // out1: nd = phi·G2T / 1024 ; out = BN(nd·WqT)+detect ; batch = mb>>5
        fa.f[0] = FO{phi, G2T, WqT, bq_c, gq_c, betq_c, mq_c, vq_c, detect_c,
                     8192L * 512, 5, 1.f / 1024.f};
        // out0: na = theta·G1T / 4096 ; out = BN(na·WwT)+aim ; batch = mb>>3
        fa.f[1] = FO{theta, G1T, WwT, bw_c, gw_c, betw_c, mw_c, vw_c, aim_c,
                     0, 3, 1.f / 4096.f};
        fused_out<<<320, blk, 0, stream>>>(fa, flag);
    }
}

// Round 9
// 352.366 us; speedup vs baseline: 3.2258x; 1.1375x over previous
//
#include <hip/hip_runtime.h>

typedef unsigned short ushort_t;
typedef unsigned int uint32;
typedef __bf16 bf16x8 __attribute__((ext_vector_type(8)));
typedef float f32x4 __attribute__((ext_vector_type(4)));
typedef uint32 u32x4 __attribute__((ext_vector_type(4)));
typedef uint32 u32x2 __attribute__((ext_vector_type(2)));

typedef __attribute__((address_space(3))) uint32 as3_u32;
typedef const __attribute__((address_space(1))) uint32 as1_u32c;

// async global->LDS, 16B per lane; LDS dest = wave-uniform base + lane*16
__device__ __forceinline__ void gl_lds16(const ushort_t* g, ushort_t* l) {
    __builtin_amdgcn_global_load_lds((as1_u32c*)g, (as3_u32*)l, 16, 0, 0);
}

__device__ __forceinline__ float bf2f(ushort_t u) {
    uint32 x = ((uint32)u) << 16;
    return __builtin_bit_cast(float, x);
}
__device__ __forceinline__ ushort_t f2bf(float f) {
    uint32 x = __builtin_bit_cast(uint32, f);
    x += 0x7fffu + ((x >> 16) & 1u);   // RNE
    return (ushort_t)(x >> 16);
}
__device__ __forceinline__ void ld4bf(const ushort_t* p, float* f) {
    const u32x2 w = *(const u32x2*)p;
    f[0] = bf2f((ushort_t)(w[0] & 0xffffu)); f[1] = bf2f((ushort_t)(w[0] >> 16));
    f[2] = bf2f((ushort_t)(w[1] & 0xffffu)); f[3] = bf2f((ushort_t)(w[1] >> 16));
}
__device__ __forceinline__ u32x2 pk4bf(const float* v) {
    u32x2 pk;
    pk[0] = (uint32)f2bf(v[0]) | ((uint32)f2bf(v[1]) << 16);
    pk[1] = (uint32)f2bf(v[2]) | ((uint32)f2bf(v[3]) << 16);
    return pk;
}

// fused dtype-sniff + small-vector canon
struct VecArgs { const void* s[14]; ushort_t* d[14]; int n[14]; };
__global__ void sniff_vec_kernel(const uint32* __restrict__ src, int* __restrict__ flag,
                                 VecArgs a) {
    __shared__ int cnt;
    if (threadIdx.x == 0) cnt = 0;
    __syncthreads();
    if (threadIdx.x < 64) {
        int weird = 0;
        for (int c = 0; c < 4; c++) {
            uint32 w = src[threadIdx.x * 4 + c];
            uint32 e = (w >> 7) & 0xFFu;
            weird += (e < 64u) || (e >= 192u);
        }
        if (weird) atomicAdd(&cnt, weird);
    }
    __syncthreads();
    const bool isf32 = (cnt > 32);
    if (threadIdx.x == 0) *flag = isf32 ? 1 : 0;
    const int t = threadIdx.x;
    for (int seg = 0; seg < 14; seg++) {
        const int n = a.n[seg];
        if (isf32) {
            const float* s = (const float*)a.s[seg];
            for (int i = t; i < n; i += 256) a.d[seg][i] = f2bf(s[i]);
        } else {
            const ushort_t* s = (const ushort_t*)a.s[seg];
            for (int i = t; i < n; i += 256) a.d[seg][i] = s[i];
        }
    }
}

// all remaining canon work in ONE launch
struct WtArgs { const void* s[6]; ushort_t* d[6]; int R[6]; int C[6]; };
__global__ void canon_all(const void* __restrict__ dsrc, ushort_t* __restrict__ ddst,
                          const void* __restrict__ asrc, ushort_t* __restrict__ adst,
                          WtArgs wa, const int* __restrict__ flag) {
    const bool isf32 = (*flag != 0);
    const int b = blockIdx.x;
    if (b < 3072) {
        const void* src; ushort_t* dst; long n; int b0, nb;
        if (b < 2048) { src = dsrc; dst = ddst; n = 16777216; b0 = b; nb = 2048; }
        else          { src = asrc; dst = adst; n = 4194304;  b0 = b - 2048; nb = 1024; }
        long i = ((long)b0 * 256 + threadIdx.x) * 8;
        const long stride = (long)nb * 256 * 8;
        if (isf32) {
            const float* s = (const float*)src;
            for (; i < n; i += stride) {
                const f32x4 a = *(const f32x4*)(s + i);
                const f32x4 c = *(const f32x4*)(s + i + 4);
                u32x4 o;
                o[0] = (uint32)f2bf(a[0]) | ((uint32)f2bf(a[1]) << 16);
                o[1] = (uint32)f2bf(a[2]) | ((uint32)f2bf(a[3]) << 16);
                o[2] = (uint32)f2bf(c[0]) | ((uint32)f2bf(c[1]) << 16);
                o[3] = (uint32)f2bf(c[2]) | ((uint32)f2bf(c[3]) << 16);
                *(u32x4*)(dst + i) = o;
            }
        } else {
            const ushort_t* s = (const ushort_t*)src;
            for (; i < n; i += stride)
                *(u32x4*)(dst + i) = *(const u32x4*)(s + i);
        }
    } else {
        const int local = b - 3072;
        const int wsel = local >> 8;
        const int rem = local & 255;
        const int tr = rem >> 4, tc = rem & 15;
        const int R = wa.R[wsel], C = wa.C[wsel];
        if (tc * 32 >= C || tr * 32 >= R) return;
        __shared__ float s[32][33];
        const int t = threadIdx.x;
        const int r = t >> 3, c4 = (t & 7) * 4;
        const long sbase = (long)(tr * 32 + r) * C + tc * 32 + c4;
        if (isf32) {
            const float* S = (const float*)wa.s[wsel];
            const f32x4 v = *(const f32x4*)(S + sbase);
            for (int u = 0; u < 4; u++) s[r][c4 + u] = v[u];
        } else {
            const ushort_t* S = (const ushort_t*)wa.s[wsel];
            for (int u = 0; u < 4; u++) s[r][c4 + u] = bf2f(S[sbase + u]);
        }
        __syncthreads();
        float tv[4];
        for (int u = 0; u < 4; u++) tv[u] = s[c4 + u][r];
        *(u32x2*)(wa.d[wsel] + (long)(tc * 32 + r) * R + tr * 32 + c4) = pk4bf(tv);
    }
}

// reduce 8 fp32 split-K partial slices -> plain bf16 G (scale folded in).
// blocks 0..1023: zz = b>>6 selects (matrix,batch); 64 blocks per 65536-elem G.
__global__ void reduce_g_kernel(const float* __restrict__ P1, const float* __restrict__ P2,
                                ushort_t* __restrict__ G1, ushort_t* __restrict__ G2) {
    const int bxv = blockIdx.x;
    const int zz = bxv >> 6;                    // 0..15
    const float* P = (zz < 8) ? P1 : P2;
    ushort_t* G    = (zz < 8) ? G1 : G2;
    const float alpha = (zz < 8) ? (1.f / 4096.f) : (1.f / 1024.f);
    const int b = zz & 7;
    const long off = ((long)(bxv & 63) * 256 + threadIdx.x) * 4;
    const float* base = P + (long)b * 8 * 65536 + off;
    f32x4 acc = {0.f, 0.f, 0.f, 0.f};
    for (int kc = 0; kc < 8; kc++) acc += *(const f32x4*)(base + (long)kc * 65536);
    float v[4] = {acc[0] * alpha, acc[1] * alpha, acc[2] * alpha, acc[3] * alpha};
    *(u32x2*)(G + (long)b * 65536 + off) = pk4bf(v);
}

#define BM 128
#define BN 128
#define BK 32
#define LDSH (BM * BK)
#define NBUF 3
#define BIGN (1 << 30)

enum { EPI_BIAS = 0, EPI_BIASR = 1, EPI_SCALE = 2, EPI_BN = 3, EPI_PART = 4 };

struct GP {
    const ushort_t* A; const ushort_t* B; void* Cv; ushort_t* CT;
    const ushort_t* bias; const ushort_t* gamma; const ushort_t* beta;
    const ushort_t* mean; const ushort_t* var; const ushort_t* res;
    long coff, sA, sB, sC;
    int K, lda, ldb, ldc, cnmax, ldT, bshift;
    float alpha;
};
struct GP2 { GP g[2]; };

// NT GEMM (r6-proven): depth-3 rotating LDS pipeline, one barrier per K-step.
// B offset: bz*sB (split-K / per-z) OR (by>>bshift)*sB (per-batch B panels).
// DUALT CT gets per-bz offset via sC (conv uses bz=0/sC=0; M-launch uses it).
template <int EPI, bool DYNOUT, bool DUALT, bool SWAP>
__global__ __launch_bounds__(256) void gemm_nt(GP2 ga, int ysplit, int zsplit,
                                               const int* __restrict__ flag)
{
    __shared__ __align__(16) ushort_t As[NBUF * LDSH];
    __shared__ __align__(16) ushort_t Bs[NBUF * LDSH];

    const bool isf32 = DYNOUT ? (*flag != 0) : false;

    const uint32 gx = gridDim.x, gy = gridDim.y;
    const uint32 nwg = gx * gy * gridDim.z;
    const uint32 lid = blockIdx.x + gx * (blockIdx.y + gy * blockIdx.z);
    const uint32 swz = (lid & 7u) * (nwg >> 3) + (lid >> 3);
    const uint32 bx = swz % gx, t1 = swz / gx;
    int by = (int)(t1 % gy), bz = (int)(t1 / gy);

    int sel = 0;
    if (by >= ysplit) { by -= ysplit; sel = 1; }
    if (bz >= zsplit) { bz -= zsplit; sel = 1; }
    const GP& p = ga.g[sel];

    const ushort_t* A = p.A + (long)bz * p.sA;
    const ushort_t* B = p.B + ((long)bz + (long)(by >> p.bshift)) * p.sB;
    const long cbase = p.coff + (long)bz * p.sC;
    const int lda = p.lda, ldb = p.ldb, ldc = p.ldc, K = p.K;

    const int tid  = threadIdx.x;
    const int lane = tid & 63;
    const int w    = tid >> 6;
    const int wr   = w >> 1, wc = w & 1;
    const int lr   = lane & 15, q = lane >> 4;

    const int m0 = by * BM;
    const int n0 = bx * BN;

    const int lrow = lane >> 2, lu = lane & 3;
    const int us = (lu ^ ((lrow >> 1) & 3)) * 8;
    const int ra0 = w * 32 + lrow, ra1 = w * 32 + 16 + lrow;
    const ushort_t* Ar0 = A + (long)(m0 + ra0) * lda + us;
    const ushort_t* Ar1 = A + (long)(m0 + ra1) * lda + us;
    const ushort_t* Br0 = B + (long)(n0 + ra0) * ldb + us;
    const ushort_t* Br1 = B + (long)(n0 + ra1) * ldb + us;
    ushort_t* sA0 = &As[(w * 2 + 0) * 512];
    ushort_t* sA1 = &As[(w * 2 + 1) * 512];
    ushort_t* sB0 = &Bs[(w * 2 + 0) * 512];
    ushort_t* sB1 = &Bs[(w * 2 + 1) * 512];

    const int swq = (q ^ ((lr >> 1) & 3)) * 8;

    f32x4 acc[4][4];
#pragma unroll
    for (int i = 0; i < 4; i++)
#pragma unroll
        for (int j = 0; j < 4; j++) acc[i][j] = (f32x4){0.f, 0.f, 0.f, 0.f};

    const int nt = K / BK;
    {
        gl_lds16(Ar0, sA0); gl_lds16(Ar1, sA1);
        gl_lds16(Br0, sB0); gl_lds16(Br1, sB1);
        if (nt > 1) {
            gl_lds16(Ar0 + BK, sA0 + LDSH); gl_lds16(Ar1 + BK, sA1 + LDSH);
            gl_lds16(Br0 + BK, sB0 + LDSH); gl_lds16(Br1 + BK, sB1 + LDSH);
        }
    }

    int c0 = 0, c2 = 2;
    for (int t = 0; t < nt; ++t) {
        if (t + 1 < nt) asm volatile("s_waitcnt vmcnt(4)" ::: "memory");
        else            asm volatile("s_waitcnt vmcnt(0)" ::: "memory");
        __builtin_amdgcn_s_barrier();
        __builtin_amdgcn_sched_barrier(0);

        if (t + 2 < nt) {
            const int nb = c2 * LDSH;
            const int kn = (t + 2) * BK;
            gl_lds16(Ar0 + kn, sA0 + nb); gl_lds16(Ar1 + kn, sA1 + nb);
            gl_lds16(Br0 + kn, sB0 + nb); gl_lds16(Br1 + kn, sB1 + nb);
        }
        __builtin_amdgcn_sched_barrier(0);

        const ushort_t* Ab = As + c0 * LDSH;
        const ushort_t* Bb = Bs + c0 * LDSH;
        bf16x8 af[4], bfr[4];
#pragma unroll
        for (int i = 0; i < 4; i++)
            af[i] = __builtin_bit_cast(bf16x8,
                *(const u32x4*)(&Ab[(wr * 64 + i * 16 + lr) * BK + swq]));
#pragma unroll
        for (int j = 0; j < 4; j++)
            bfr[j] = __builtin_bit_cast(bf16x8,
                *(const u32x4*)(&Bb[(wc * 64 + j * 16 + lr) * BK + swq]));
#pragma unroll
        for (int i = 0; i < 4; i++)
#pragma unroll
            for (int j = 0; j < 4; j++) {
                if constexpr (SWAP)
                    acc[i][j] = __builtin_amdgcn_mfma_f32_16x16x32_bf16(bfr[j], af[i], acc[i][j], 0, 0, 0);
                else
                    acc[i][j] = __builtin_amdgcn_mfma_f32_16x16x32_bf16(af[i], bfr[j], acc[i][j], 0, 0, 0);
            }
        __builtin_amdgcn_sched_barrier(0);

        c0 = (c0 + 1 == NBUF) ? 0 : c0 + 1;
        c2 = (c2 + 1 == NBUF) ? 0 : c2 + 1;
    }

    if constexpr (SWAP) {
        // D layout (swapped): thread holds C[m0+..+lr][coln..coln+3] -> vector epi
#pragma unroll
        for (int j = 0; j < 4; j++) {
            const int coln = n0 + wc * 64 + j * 16 + q * 4;
            float sc4[4], sh4[4];
            if constexpr (EPI == EPI_BIAS) {
                float bb[4]; ld4bf(p.bias + coln, bb);
#pragma unroll
                for (int r = 0; r < 4; r++) { sc4[r] = 1.f; sh4[r] = bb[r]; }
            } else if constexpr (EPI == EPI_SCALE) {
#pragma unroll
                for (int r = 0; r < 4; r++) { sc4[r] = p.alpha; sh4[r] = 0.f; }
            } else if constexpr (EPI == EPI_BN) {
                float bb[4], g[4], bt[4], mn[4], vr[4];
                ld4bf(p.bias + coln, bb); ld4bf(p.gamma + coln, g); ld4bf(p.beta + coln, bt);
                ld4bf(p.mean + coln, mn); ld4bf(p.var + coln, vr);
#pragma unroll
                for (int r = 0; r < 4; r++) {
                    const float s = g[r] * rsqrtf(vr[r] + 1e-3f);
                    sc4[r] = s;
                    sh4[r] = s * bb[r] + bt[r] - s * mn[r];
                }
            }
#pragma unroll
            for (int i = 0; i < 4; i++) {
                const int row = m0 + wr * 64 + i * 16 + lr;
                const long off = cbase + (long)row * ldc + coln;
                float v[4];
#pragma unroll
                for (int r = 0; r < 4; r++) v[r] = acc[i][j][r];
                if constexpr (EPI == EPI_BIASR) {
                    const float bs = bf2f(p.bias[row]);
#pragma unroll
                    for (int r = 0; r < 4; r++) v[r] += bs;
                } else if constexpr (EPI == EPI_BN) {
                    float rs[4]; ld4bf(p.res + (long)row * ldc + coln, rs);
#pragma unroll
                    for (int r = 0; r < 4; r++) v[r] = sc4[r] * v[r] + sh4[r] + rs[r];
                } else if constexpr (EPI != EPI_PART) {
#pragma unroll
                    for (int r = 0; r < 4; r++) v[r] = sc4[r] * v[r] + sh4[r];
                }
                if constexpr (EPI == EPI_PART) {
                    *(f32x4*)((float*)p.Cv + off) = (f32x4){v[0], v[1], v[2], v[3]};
                } else if constexpr (DYNOUT) {
                    if (isf32) *(f32x4*)((float*)p.Cv + off) = (f32x4){v[0], v[1], v[2], v[3]};
                    else       *(u32x2*)((ushort_t*)p.Cv + off) = pk4bf(v);
                } else {
                    *(u32x2*)((ushort_t*)p.Cv + off) = pk4bf(v);
                }
            }
        }
    } else {
        // D layout: col=lane&15 -> n, row=(lane>>4)*4+reg -> m  [verified]
        const bool doC = (n0 < p.cnmax);
#pragma unroll
        for (int j = 0; j < 4; j++) {
            const int col = n0 + wc * 64 + j * 16 + lr;
            float bs = 0.f;
            if constexpr (EPI == EPI_BIAS) bs = bf2f(p.bias[col]);
#pragma unroll
            for (int i = 0; i < 4; i++) {
                const int rowbase = m0 + wr * 64 + i * 16 + q * 4;
                ushort_t tmp[4];
#pragma unroll
                for (int r = 0; r < 4; r++) {
                    const int row = rowbase + r;
                    float v = acc[i][j][r];
                    if constexpr (EPI == EPI_BIAS) v += bs;
                    else if constexpr (EPI == EPI_BIASR) v += bf2f(p.bias[row]);
                    else if constexpr (EPI == EPI_SCALE) v *= p.alpha;
                    const long off = cbase + (long)row * ldc + col;
                    if constexpr (EPI == EPI_PART) {
                        ((float*)p.Cv)[off] = v;
                    } else {
                        const ushort_t us2 = f2bf(v);
                        tmp[r] = us2;
                        if (doC) ((ushort_t*)p.Cv)[off] = us2;
                    }
                }
                if constexpr (DUALT) {
                    u32x2 pk;
                    pk[0] = (uint32)tmp[0] | ((uint32)tmp[1] << 16);
                    pk[1] = (uint32)tmp[2] | ((uint32)tmp[3] << 16);
                    *(u32x2*)(p.CT + (long)bz * p.sC + (long)col * p.ldT + rowbase) = pk;
                }
            }
        }
    }
}

extern "C" void kernel_launch(void* const* d_in, const int* in_sizes, int n_in,
                              void* d_out, int out_size, void* d_ws, size_t ws_size,
                              hipStream_t stream)
{
    int* flag = (int*)d_ws;
    ushort_t* base = (ushort_t*)((char*)d_ws + 16);
    long o = 0;
    ushort_t* detect_c = base + o; o += 16777216;   // [32768][512]
    ushort_t* aim_c    = base + o; o += 4194304;    // [8192][512]
    ushort_t* WpgT = base + o; o += 262144;         // [512][512] = [WpT; WgT]
    ushort_t* WtgT = base + o; o += 262144;         // [512][512] = [WtT; WgT]
    ushort_t* WwT  = base + o; o += 131072;         // [512][256]
    ushort_t* WqT  = base + o; o += 131072;
    ushort_t* bpg_c  = base + o; o += 512;
    ushort_t* btg_c  = base + o; o += 512;
    ushort_t* bw_c   = base + o; o += 512;
    ushort_t* gw_c   = base + o; o += 512;
    ushort_t* betw_c = base + o; o += 512;
    ushort_t* mw_c   = base + o; o += 512;
    ushort_t* vw_c   = base + o; o += 512;
    ushort_t* bq_c   = base + o; o += 512;
    ushort_t* gq_c   = base + o; o += 512;
    ushort_t* betq_c = base + o; o += 512;
    ushort_t* mq_c   = base + o; o += 512;
    ushort_t* vq_c   = base + o; o += 512;
    ushort_t* phi    = base + o; o += 8388608;      // [32768][256]
    ushort_t* PT     = base + o; o += 16777216;     // [512][32768]: phiT + d_xT
    ushort_t* theta  = base + o; o += 2097152;      // [8192][256]
    ushort_t* TT     = base + o; o += 4194304;      // [512][8192]: thetaT + a_xT
    ushort_t* G1     = base + o; o += 524288;       // [8][256][256] bf16 (plain)
    ushort_t* G2     = base + o; o += 524288;
    ushort_t* M1T    = base + o; o += 1048576;      // [8][512][256] = (G1/4096 · Ww)^T
    ushort_t* M2T    = base + o; o += 1048576;      // [8][512][256] = (G2/1024 · Wq)^T
    ushort_t* U      = base + o; o += 16777216;     // P1,P2 fp32 (64 slices each)
    float* P1 = (float*)U;
    float* P2 = P1 + 4194304;
    ushort_t* phiT = PT;
    ushort_t* d_xT = PT + 8388608;
    ushort_t* thetaT = TT;
    ushort_t* a_xT = TT + 2097152;

    VecArgs va;
    const int vidx[14] = {7, 3, 5, 3, 9, 10, 11, 12, 13, 15, 16, 17, 18, 19};
    ushort_t* vdst[14] = {bpg_c, bpg_c + 256, btg_c, btg_c + 256,
                          bw_c, gw_c, betw_c, mw_c, vw_c,
                          bq_c, gq_c, betq_c, mq_c, vq_c};
    const int vn[14] = {256, 256, 256, 256, 512, 512, 512, 512, 512, 512, 512, 512, 512, 512};
    for (int i = 0; i < 14; i++) { va.s[i] = d_in[vidx[i]]; va.d[i] = vdst[i]; va.n[i] = vn[i]; }
    sniff_vec_kernel<<<1, 256, 0, stream>>>((const uint32*)d_in[0], flag, va);

    WtArgs wa;
    wa.s[0] = d_in[6];  wa.d[0] = WpgT;              wa.R[0] = 512; wa.C[0] = 256;
    wa.s[1] = d_in[2];  wa.d[1] = WpgT + 256 * 512;  wa.R[1] = 512; wa.C[1] = 256;
    wa.s[2] = d_in[4];  wa.d[2] = WtgT;              wa.R[2] = 512; wa.C[2] = 256;
    wa.s[3] = d_in[2];  wa.d[3] = WtgT + 256 * 512;  wa.R[3] = 512; wa.C[3] = 256;
    wa.s[4] = d_in[8];  wa.d[4] = WwT;               wa.R[4] = 256; wa.C[4] = 512;
    wa.s[5] = d_in[14]; wa.d[5] = WqT;               wa.R[5] = 256; wa.C[5] = 512;
    canon_all<<<4608, 256, 0, stream>>>(d_in[0], detect_c, d_in[1], aim_c, wa, flag);

    const dim3 blk(256);
    const ushort_t* np = nullptr;
    ushort_t* npm = nullptr;

    // merged convs: phi/theta + phiT/d_xT + thetaT/a_xT (one read of each act)
    {
        GP2 g;
        g.g[0] = GP{detect_c, WpgT, phi, PT, bpg_c, np, np, np, np, np,
                    0, 0, 0, 0, 512, 512, 512, 256, 256, 32768, 30, 1.f};
        g.g[1] = GP{aim_c, WtgT, theta, TT, btg_c, np, np, np, np, np,
                    0, 0, 0, 0, 512, 512, 512, 256, 256, 8192, 30, 1.f};
        gemm_nt<EPI_BIAS, false, true, false><<<dim3(4, 320, 1), blk, 0, stream>>>(
            g, 256, BIGN, flag);
    }

    // merged split-K partials: G1 (bz<64, K-chunk 512) + G2 (K-chunk 128)
    {
        GP2 g;
        g.g[0] = GP{phiT, d_xT, P1, npm, np, np, np, np, np, np,
                    0, 512, 512, 65536, 512, 32768, 32768, 256, BIGN, 0, 30, 1.f};
        g.g[1] = GP{thetaT, a_xT, P2, npm, np, np, np, np, np, np,
                    0, 128, 128, 65536, 128, 8192, 8192, 256, BIGN, 0, 30, 1.f};
        gemm_nt<EPI_PART, false, false, true><<<dim3(2, 2, 128), blk, 0, stream>>>(
            g, BIGN, 64, flag);
    }

    // reduce partials -> plain bf16 G (scale folded): 1024 blocks
    reduce_g_kernel<<<1024, blk, 0, stream>>>(P1, P2, G1, G2);

    // tiny per-batch M = G · W^T, stored transposed (CT path): 128 blocks.
    // set0: M1T[b] = ((G1[b]) · Ww)^T ; set1: M2T[b] = ((G2[b]) · Wq)^T
    {
        GP2 g;
        g.g[0] = GP{G1, WwT, npm, M1T, np, np, np, np, np, np,
                    0, 65536, 0, 131072, 256, 256, 256, 512, 0, 256, 30, 1.f};
        g.g[1] = GP{G2, WqT, npm, M2T, np, np, np, np, np, np,
                    0, 65536, 0, 131072, 256, 256, 256, 512, 0, 256, 30, 1.f};
        gemm_nt<EPI_SCALE, false, true, false><<<dim3(4, 2, 16), blk, 0, stream>>>(
            g, BIGN, 8, flag);
    }

    // outputs: out1 = BN(phi·M2[b] + bq) + detect ; out0 = BN(theta·M1[b] + bw) + aim
    // B = per-batch M^T panel selected via by>>bshift (batch stride 131072).
    {
        GP2 g;
        g.g[0] = GP{phi, M2T, d_out, npm, bq_c, gq_c, betq_c, mq_c, vq_c, detect_c,
                    8192L * 512, 0, 131072, 0, 256, 256, 256, 512, BIGN, 0, 5, 1.f};
        g.g[1] = GP{theta, M1T, d_out, npm, bw_c, gw_c, betw_c, mw_c, vw_c, aim_c,
                    0, 0, 131072, 0, 256, 256, 256, 512, BIGN, 0, 3, 1.f};
        gemm_nt<EPI_BN, true, false, true><<<dim3(4, 320, 1), blk, 0, stream>>>(
            g, 256, BIGN, flag);
    }
}